// Round 1
// baseline (439.785 us; speedup 1.0000x reference)
//
#include <hip/hip_runtime.h>
#include <stdint.h>

typedef unsigned int  u32;
typedef unsigned short u16;
typedef __bf16 v8bf __attribute__((ext_vector_type(8)));
typedef float  v4f  __attribute__((ext_vector_type(4)));

#define N_INST 256
#define BATCH  128
#define IN_DIM 1024
#define L_DIM  512
#define M_TOT  (N_INST*BATCH)   // 32768

#define BM 128
#define BN 128       // packed (interleaved V/U) cols per block = 64 L pairs
#define BK 64
#define LDK 72       // padded LDS k-stride in bf16 elems (144 B, 16B-aligned)
#define KITERS (IN_DIM/BK)

// ws layout:
//   [0, 2MB)   : Wpk bf16 [1024 packed rows][1024 k]; packed row n' = 2*l + (0=V,1=U)
//   [2MB, 3MB) : partial fp32 [8][M_TOT]

// pack bf16(a) into low16, bf16(b) into high16 (RNE)
__device__ inline u32 f2bf_pk(float a, float b){
  u32 ua = __builtin_bit_cast(u32, a);
  u32 ub = __builtin_bit_cast(u32, b);
  ua = (ua + 0x7FFFu + ((ua >> 16) & 1u)) >> 16;
  ub = (ub + 0x7FFFu + ((ub >> 16) & 1u)) & 0xFFFF0000u;
  return ua | ub;
}

__global__ void prep_w(const float* __restrict__ v, const float* __restrict__ u,
                       u16* __restrict__ wpk){
  int t = blockIdx.x * 256 + threadIdx.x;     // 131072 threads
  int o = t * 8;                               // 8 consecutive k of one packed row
  int np = o >> 10;                            // packed row index
  int k0 = o & 1023;
  int l  = np >> 1;
  const float* src = (np & 1) ? u : v;
  u32 out[4];
#pragma unroll
  for (int i = 0; i < 4; ++i){
    float a = src[(size_t)(k0 + 2*i    ) * L_DIM + l];
    float b = src[(size_t)(k0 + 2*i + 1) * L_DIM + l];
    out[i] = f2bf_pk(a, b);
  }
  *reinterpret_cast<uint4*>(wpk + o) = make_uint4(out[0], out[1], out[2], out[3]);
}

__launch_bounds__(256)
__global__ void gemm_score(const float* __restrict__ x, const u16* __restrict__ wpk,
                           const float* __restrict__ w, float* __restrict__ partial){
  __shared__ u16  As[BM * LDK];
  __shared__ u16  Bs[BN * LDK];
  __shared__ float ssum[BM];

  const int tid  = threadIdx.x;
  const int nblk = blockIdx.x;     // 0..7
  const int mblk = blockIdx.y;     // 0..255
  const int m0   = mblk * BM;

  const int lane = tid & 63;
  const int wave = tid >> 6;
  const int wm   = (wave >> 1) * 64;
  const int wn   = (wave & 1) * 64;
  const int q    = lane >> 4;
  const int c    = lane & 15;

  if (tid < BM) ssum[tid] = 0.f;

  // A staging: inst j (0..7): rows j*16 + (tid>>4), 4 floats at (tid&15)*4
  const int arow = tid >> 4;
  const int akk  = (tid & 15) * 4;
  // B staging: inst j (0..3): rows j*32 + (tid>>3), 8 bf16 at (tid&7)*8
  const int brow = tid >> 3;
  const int bkk  = (tid & 7) * 8;

  const float* xa = x   + (size_t)m0 * IN_DIM;
  const u16*   wb = wpk + (size_t)(nblk * BN) * IN_DIM;

  float4 areg[8];
  uint4  breg[4];

  auto load_tile = [&](int k0){
#pragma unroll
    for (int j = 0; j < 8; ++j){
      int row = j*16 + arow;
      areg[j] = *reinterpret_cast<const float4*>(xa + (size_t)row*IN_DIM + k0 + akk);
    }
#pragma unroll
    for (int j = 0; j < 4; ++j){
      int row = j*32 + brow;
      breg[j] = *reinterpret_cast<const uint4*>(wb + (size_t)row*IN_DIM + k0 + bkk);
    }
  };

  v4f acc[4][4];
#pragma unroll
  for (int i = 0; i < 4; ++i)
#pragma unroll
    for (int j = 0; j < 4; ++j)
      acc[i][j] = (v4f){0.f, 0.f, 0.f, 0.f};

  load_tile(0);
  for (int kt = 0; kt < KITERS; ++kt){
    // regs -> LDS (convert A fp32 -> bf16)
#pragma unroll
    for (int j = 0; j < 8; ++j){
      int row = j*16 + arow;
      uint2 p;
      p.x = f2bf_pk(areg[j].x, areg[j].y);
      p.y = f2bf_pk(areg[j].z, areg[j].w);
      *reinterpret_cast<uint2*>(&As[row*LDK + akk]) = p;
    }
#pragma unroll
    for (int j = 0; j < 4; ++j){
      int row = j*32 + brow;
      *reinterpret_cast<uint4*>(&Bs[row*LDK + bkk]) = breg[j];
    }
    __syncthreads();
    if (kt + 1 < KITERS) load_tile((kt + 1) * BK);   // overlaps MFMA below
#pragma unroll
    for (int kk = 0; kk < 2; ++kk){
      v8bf af[4], bfr[4];
      const int kb = kk*32 + q*8;
#pragma unroll
      for (int i = 0; i < 4; ++i)
        af[i] = *reinterpret_cast<const v8bf*>(&As[(wm + i*16 + c)*LDK + kb]);
#pragma unroll
      for (int j = 0; j < 4; ++j)
        bfr[j] = *reinterpret_cast<const v8bf*>(&Bs[(wn + j*16 + c)*LDK + kb]);
#pragma unroll
      for (int i = 0; i < 4; ++i)
#pragma unroll
        for (int j = 0; j < 4; ++j)
          acc[i][j] = __builtin_amdgcn_mfma_f32_16x16x32_bf16(af[i], bfr[j], acc[i][j], 0, 0, 0);
    }
    __syncthreads();
  }

  // epilogue: contrib = tanh(h_pre)*sigmoid(g_pre)*w[l]; packed cols alternate V(even)/U(odd)
  float wl[4];
#pragma unroll
  for (int j = 0; j < 4; ++j)
    wl[j] = w[nblk*64 + (wn >> 1) + j*8 + (c >> 1)];

  const int codd = c & 1;
#pragma unroll
  for (int i = 0; i < 4; ++i){
    float rs[4] = {0.f, 0.f, 0.f, 0.f};
#pragma unroll
    for (int j = 0; j < 4; ++j){
#pragma unroll
      for (int r = 0; r < 4; ++r){
        float val = acc[i][j][r];
        // even lane computes tanh (V col), odd lane computes sigmoid (U col)
        float y = codd ? val : 2.f*val;
        float s = 1.f / (1.f + __expf(-y));
        float t = codd ? s : (2.f*s - 1.f);
        float part = __shfl_xor(t, 1, 64);
        rs[r] += codd ? 0.f : (t * part * wl[j]);
      }
    }
#pragma unroll
    for (int r = 0; r < 4; ++r){
      float v2 = rs[r];
      v2 += __shfl_xor(v2, 1, 64);
      v2 += __shfl_xor(v2, 2, 64);
      v2 += __shfl_xor(v2, 4, 64);
      v2 += __shfl_xor(v2, 8, 64);
      if (c == 0) atomicAdd(&ssum[wm + i*16 + q*4 + r], v2);
    }
  }
  __syncthreads();
  if (tid < BM) partial[(size_t)nblk * M_TOT + m0 + tid] = ssum[tid];
}

__global__ void softmax_inst(const float* __restrict__ partial, float* __restrict__ out){
  __shared__ float red[N_INST];
  const int b = blockIdx.x;
  const int n = threadIdx.x;
  float s = 0.f;
#pragma unroll
  for (int i = 0; i < 8; ++i) s += partial[(size_t)i * M_TOT + n*BATCH + b];
  red[n] = s; __syncthreads();
  for (int st = N_INST/2; st > 0; st >>= 1){
    if (n < st) red[n] = fmaxf(red[n], red[n + st]);
    __syncthreads();
  }
  float mx = red[0]; __syncthreads();
  float e = __expf(s - mx);
  red[n] = e; __syncthreads();
  for (int st = N_INST/2; st > 0; st >>= 1){
    if (n < st) red[n] += red[n + st];
    __syncthreads();
  }
  out[n*BATCH + b] = e / red[0];
}

extern "C" void kernel_launch(void* const* d_in, const int* in_sizes, int n_in,
                              void* d_out, int out_size, void* d_ws, size_t ws_size,
                              hipStream_t stream) {
  const float* x = (const float*)d_in[0];
  const float* v = (const float*)d_in[1];
  const float* u = (const float*)d_in[2];
  const float* w = (const float*)d_in[3];
  u16*   wpk     = (u16*)d_ws;
  float* partial = (float*)((char*)d_ws + (size_t)1024 * IN_DIM * sizeof(u16));
  float* out     = (float*)d_out;

  prep_w<<<dim3(512), dim3(256), 0, stream>>>(v, u, wpk);
  gemm_score<<<dim3(8, 256), dim3(256), 0, stream>>>(x, wpk, w, partial);
  softmax_inst<<<dim3(BATCH), dim3(N_INST), 0, stream>>>(partial, out);
}

// Round 2
// 318.596 us; speedup vs baseline: 1.3804x; 1.3804x over previous
//
#include <hip/hip_runtime.h>
#include <stdint.h>

typedef unsigned int  u32;
typedef unsigned short u16;
typedef __bf16 v8bf __attribute__((ext_vector_type(8)));
typedef float  v4f  __attribute__((ext_vector_type(4)));

#define N_INST 256
#define BATCH  128
#define IN_DIM 1024
#define L_DIM  512
#define M_TOT  (N_INST*BATCH)   // 32768

#define BM 128
#define BN 128       // packed (interleaved V/U) cols per block = 64 L pairs
#define BK 64        // bf16 elems = 128 B = 8 chunks of 16 B per row
#define KITERS (IN_DIM/BK)

// ws layout:
//   [0, 64MB)        : x_bf16 [32768][1024]
//   [64MB, 66MB)     : Wpk bf16 [1024 packed rows][1024 k]; row n' = 2*l + (0=V,1=U)
//   [66MB, 67MB)     : partial fp32 [8][M_TOT]
#define XB_BYTES   ((size_t)M_TOT * IN_DIM * 2)      // 67108864
#define WPK_BYTES  ((size_t)1024 * IN_DIM * 2)       // 2097152

// pack bf16(a) low16, bf16(b) high16 (RNE)
__device__ inline u32 f2bf_pk(float a, float b){
  u32 ua = __builtin_bit_cast(u32, a);
  u32 ub = __builtin_bit_cast(u32, b);
  ua = (ua + 0x7FFFu + ((ua >> 16) & 1u)) >> 16;
  ub = (ub + 0x7FFFu + ((ub >> 16) & 1u)) & 0xFFFF0000u;
  return ua | ub;
}

// async global->LDS, 16 B per lane; lds dst must be wave-uniform base (+lane*16 by HW)
__device__ inline void gl2lds16(const u16* g, u16* l){
  __builtin_amdgcn_global_load_lds(
      (const __attribute__((address_space(1))) u32*)(g),
      (__attribute__((address_space(3))) u32*)(l), 16, 0, 0);
}

__global__ void prep_x(const float* __restrict__ x, u16* __restrict__ xb){
  size_t o = ((size_t)blockIdx.x * 256 + threadIdx.x) * 8;
  float4 a = *reinterpret_cast<const float4*>(x + o);
  float4 b = *reinterpret_cast<const float4*>(x + o + 4);
  uint4 out;
  out.x = f2bf_pk(a.x, a.y); out.y = f2bf_pk(a.z, a.w);
  out.z = f2bf_pk(b.x, b.y); out.w = f2bf_pk(b.z, b.w);
  *reinterpret_cast<uint4*>(xb + o) = out;
}

__global__ void prep_w(const float* __restrict__ v, const float* __restrict__ u,
                       u16* __restrict__ wpk){
  int t = blockIdx.x * 256 + threadIdx.x;     // 131072 threads
  int o = t * 8;                               // 8 consecutive k of one packed row
  int np = o >> 10;                            // packed row index
  int k0 = o & 1023;
  int l  = np >> 1;
  const float* src = (np & 1) ? u : v;
  u32 out[4];
#pragma unroll
  for (int i = 0; i < 4; ++i){
    float a = src[(size_t)(k0 + 2*i    ) * L_DIM + l];
    float b = src[(size_t)(k0 + 2*i + 1) * L_DIM + l];
    out[i] = f2bf_pk(a, b);
  }
  *reinterpret_cast<uint4*>(wpk + o) = make_uint4(out[0], out[1], out[2], out[3]);
}

__launch_bounds__(256)
__global__ void gemm_score(const u16* __restrict__ xb, const u16* __restrict__ wpk,
                           const float* __restrict__ w, float* __restrict__ partial){
  // unpadded (global_load_lds requirement); XOR-swizzled chunks kill bank conflicts
  __shared__ __align__(16) u16 As[BM * BK];   // 16 KB
  __shared__ __align__(16) u16 Bs[BN * BK];   // 16 KB
  __shared__ float ssum[BM];

  const int tid  = threadIdx.x;
  const int nblk = blockIdx.x;     // 0..7
  const int mblk = blockIdx.y;     // 0..255
  const int m0   = mblk * BM;

  const int lane = tid & 63;
  const int wave = tid >> 6;
  const int wm   = (wave >> 1) * 64;
  const int wn   = (wave & 1) * 64;
  const int q    = lane >> 4;
  const int c    = lane & 15;

  if (tid < BM) ssum[tid] = 0.f;

  // staging geometry: 16 regions of 1 KB per tile; region = wave*4+j covers rows reg*8..+7
  // lane i -> row_in_region rr=i>>3, LDS chunk i&7 which must hold global chunk (i&7)^rr
  const int rr = lane >> 3;
  const int cg = (lane & 7) ^ rr;          // swizzled source chunk (16 B units)
  const u16* ga = xb  + (size_t)m0 * IN_DIM;
  const u16* gb = wpk + (size_t)(nblk * BN) * IN_DIM;

  v4f acc[4][4];
#pragma unroll
  for (int i = 0; i < 4; ++i)
#pragma unroll
    for (int j = 0; j < 4; ++j)
      acc[i][j] = (v4f){0.f, 0.f, 0.f, 0.f};

  for (int kt = 0; kt < KITERS; ++kt){
    const int kb = kt * BK;
#pragma unroll
    for (int j = 0; j < 4; ++j){
      const int reg = wave * 4 + j;
      const int row = reg * 8 + rr;
      gl2lds16(ga + (size_t)row * IN_DIM + kb + cg * 8, &As[reg * 512 + lane * 8]);
      gl2lds16(gb + (size_t)row * IN_DIM + kb + cg * 8, &Bs[reg * 512 + lane * 8]);
    }
    __syncthreads();   // drains vmcnt; tile visible to all waves
#pragma unroll
    for (int kk = 0; kk < 2; ++kk){
      v8bf af[4], bfr[4];
#pragma unroll
      for (int i = 0; i < 4; ++i){
        const int row = wm + i*16 + c;
        const int ch  = (kk*4 + q) ^ (row & 7);
        af[i] = *reinterpret_cast<const v8bf*>(&As[row*64 + ch*8]);
      }
#pragma unroll
      for (int j = 0; j < 4; ++j){
        const int row = wn + j*16 + c;
        const int ch  = (kk*4 + q) ^ (row & 7);
        bfr[j] = *reinterpret_cast<const v8bf*>(&Bs[row*64 + ch*8]);
      }
#pragma unroll
      for (int i = 0; i < 4; ++i)
#pragma unroll
        for (int j = 0; j < 4; ++j)
          acc[i][j] = __builtin_amdgcn_mfma_f32_16x16x32_bf16(af[i], bfr[j], acc[i][j], 0, 0, 0);
    }
    __syncthreads();   // protect LDS before next tile's loads
  }

  // epilogue: contrib = tanh(h)*sigmoid(g)*w[l]; packed cols alternate V(even)/U(odd)
  float wl[4];
#pragma unroll
  for (int j = 0; j < 4; ++j)
    wl[j] = w[nblk*64 + (wn >> 1) + j*8 + (c >> 1)];

  const int codd = c & 1;
#pragma unroll
  for (int i = 0; i < 4; ++i){
    float rs[4] = {0.f, 0.f, 0.f, 0.f};
#pragma unroll
    for (int j = 0; j < 4; ++j){
#pragma unroll
      for (int r = 0; r < 4; ++r){
        float val = acc[i][j][r];
        // even lane computes tanh (V col), odd lane computes sigmoid (U col)
        float y = codd ? val : 2.f*val;
        float s = 1.f / (1.f + __expf(-y));
        float t = codd ? s : (2.f*s - 1.f);
        float part = __shfl_xor(t, 1, 64);
        rs[r] += codd ? 0.f : (t * part * wl[j]);
      }
    }
#pragma unroll
    for (int r = 0; r < 4; ++r){
      float v2 = rs[r];
      v2 += __shfl_xor(v2, 1, 64);
      v2 += __shfl_xor(v2, 2, 64);
      v2 += __shfl_xor(v2, 4, 64);
      v2 += __shfl_xor(v2, 8, 64);
      if (c == 0) atomicAdd(&ssum[wm + i*16 + q*4 + r], v2);
    }
  }
  __syncthreads();
  if (tid < BM) partial[(size_t)nblk * M_TOT + m0 + tid] = ssum[tid];
}

__global__ void softmax_inst(const float* __restrict__ partial, float* __restrict__ out){
  __shared__ float red[N_INST];
  const int b = blockIdx.x;
  const int n = threadIdx.x;
  float s = 0.f;
#pragma unroll
  for (int i = 0; i < 8; ++i) s += partial[(size_t)i * M_TOT + n*BATCH + b];
  red[n] = s; __syncthreads();
  for (int st = N_INST/2; st > 0; st >>= 1){
    if (n < st) red[n] = fmaxf(red[n], red[n + st]);
    __syncthreads();
  }
  float mx = red[0]; __syncthreads();
  float e = __expf(s - mx);
  red[n] = e; __syncthreads();
  for (int st = N_INST/2; st > 0; st >>= 1){
    if (n < st) red[n] += red[n + st];
    __syncthreads();
  }
  out[n*BATCH + b] = e / red[0];
}

extern "C" void kernel_launch(void* const* d_in, const int* in_sizes, int n_in,
                              void* d_out, int out_size, void* d_ws, size_t ws_size,
                              hipStream_t stream) {
  const float* x = (const float*)d_in[0];
  const float* v = (const float*)d_in[1];
  const float* u = (const float*)d_in[2];
  const float* w = (const float*)d_in[3];
  u16*   xb      = (u16*)d_ws;
  u16*   wpk     = (u16*)((char*)d_ws + XB_BYTES);
  float* partial = (float*)((char*)d_ws + XB_BYTES + WPK_BYTES);
  float* out     = (float*)d_out;

  prep_x<<<dim3((M_TOT*(size_t)IN_DIM)/8/256), dim3(256), 0, stream>>>(x, xb);
  prep_w<<<dim3(512), dim3(256), 0, stream>>>(v, u, wpk);
  gemm_score<<<dim3(8, 256), dim3(256), 0, stream>>>(xb, wpk, w, partial);
  softmax_inst<<<dim3(BATCH), dim3(N_INST), 0, stream>>>(partial, out);
}

// Round 3
// 312.702 us; speedup vs baseline: 1.4064x; 1.0188x over previous
//
#include <hip/hip_runtime.h>
#include <stdint.h>

typedef unsigned int  u32;
typedef unsigned short u16;
typedef __bf16 v8bf __attribute__((ext_vector_type(8)));
typedef float  v4f  __attribute__((ext_vector_type(4)));

#define N_INST 256
#define BATCH  128
#define IN_DIM 1024
#define L_DIM  512
#define M_TOT  (N_INST*BATCH)   // 32768

#define BM 128
#define BN 128       // packed (interleaved V/U) cols per block = 64 L pairs
#define BK 64        // bf16 elems = 128 B = 8 chunks of 16 B per row
#define KITERS (IN_DIM/BK)

// ws layout:
//   [0, 64MB)        : x_bf16 [32768][1024]
//   [64MB, 66MB)     : Wpk bf16 [1024 packed rows][1024 k]; row n' = 2*l + (0=V,1=U)
//   [66MB, 67MB)     : partial fp32 [8][M_TOT]
#define XB_BYTES   ((size_t)M_TOT * IN_DIM * 2)      // 67108864
#define WPK_BYTES  ((size_t)1024 * IN_DIM * 2)       // 2097152

// pack bf16(a) low16, bf16(b) high16 (RNE)
__device__ inline u32 f2bf_pk(float a, float b){
  u32 ua = __builtin_bit_cast(u32, a);
  u32 ub = __builtin_bit_cast(u32, b);
  ua = (ua + 0x7FFFu + ((ua >> 16) & 1u)) >> 16;
  ub = (ub + 0x7FFFu + ((ub >> 16) & 1u)) & 0xFFFF0000u;
  return ua | ub;
}

// async global->LDS, 16 B per lane; lds dst is wave-uniform base (+lane*16 by HW)
__device__ inline void gl2lds16(const u16* g, u16* l){
  __builtin_amdgcn_global_load_lds(
      (const __attribute__((address_space(1))) u32*)(g),
      (__attribute__((address_space(3))) u32*)(l), 16, 0, 0);
}

// fused prep: blocks [0,16384) convert x -> bf16; blocks [16384,16896) pack V/U
#define PREP_XBLKS 16384
__global__ void prep(const float* __restrict__ x, const float* __restrict__ v,
                     const float* __restrict__ u, u16* __restrict__ xb,
                     u16* __restrict__ wpk){
  const int b = blockIdx.x;
  if (b < PREP_XBLKS){
    size_t o = ((size_t)b * 256 + threadIdx.x) * 8;
    float4 a0 = *reinterpret_cast<const float4*>(x + o);
    float4 a1 = *reinterpret_cast<const float4*>(x + o + 4);
    uint4 out;
    out.x = f2bf_pk(a0.x, a0.y); out.y = f2bf_pk(a0.z, a0.w);
    out.z = f2bf_pk(a1.x, a1.y); out.w = f2bf_pk(a1.z, a1.w);
    *reinterpret_cast<uint4*>(xb + o) = out;
  } else {
    int t = (b - PREP_XBLKS) * 256 + threadIdx.x;  // 131072 threads
    int o = t * 8;
    int np = o >> 10;
    int k0 = o & 1023;
    int l  = np >> 1;
    const float* src = (np & 1) ? u : v;
    u32 out[4];
#pragma unroll
    for (int i = 0; i < 4; ++i){
      float a = src[(size_t)(k0 + 2*i    ) * L_DIM + l];
      float c = src[(size_t)(k0 + 2*i + 1) * L_DIM + l];
      out[i] = f2bf_pk(a, c);
    }
    *reinterpret_cast<uint4*>(wpk + o) = make_uint4(out[0], out[1], out[2], out[3]);
  }
}

__launch_bounds__(256)
__global__ void gemm_score(const u16* __restrict__ xb, const u16* __restrict__ wpk,
                           const float* __restrict__ w, float* __restrict__ partial){
  // unpadded (global_load_lds requirement); XOR-swizzled chunks kill bank conflicts
  __shared__ __align__(16) u16 As[BM * BK];   // 16 KB
  __shared__ __align__(16) u16 Bs[BN * BK];   // 16 KB
  __shared__ float ssum[BM];

  const int tid  = threadIdx.x;
  // XCD-aware swizzle: round-robin dispatch puts bid%8 on XCD (bid&7).
  // Give each XCD a contiguous 32-mblk slice across ALL nblk so the x tile
  // (256 KB) is reused 8x inside one L2 and wpk (2 MB) stays L2-resident.
  const u32 bid  = blockIdx.x;          // 0..2047
  const int xcd  = bid & 7;
  const int slot = bid >> 3;            // 0..255
  const int nblk = slot & 7;            // fast: cycles per x-tile
  const int mblk = xcd * 32 + (slot >> 3);
  const int m0   = mblk * BM;

  const int lane = tid & 63;
  const int wave = tid >> 6;
  const int wm   = (wave >> 1) * 64;
  const int wn   = (wave & 1) * 64;
  const int q    = lane >> 4;
  const int c    = lane & 15;

  if (tid < BM) ssum[tid] = 0.f;

  // staging: 16 regions of 1 KB per tile; region = wave*4+j covers rows reg*8..+7
  // lane i -> row_in_region rr=i>>3, LDS chunk i&7 holds global chunk (i&7)^rr
  const int rr = lane >> 3;
  const int cg = (lane & 7) ^ rr;          // swizzled source chunk (16 B units)
  const u16* ga = xb  + (size_t)m0 * IN_DIM;
  const u16* gb = wpk + (size_t)(nblk * BN) * IN_DIM;

  v4f acc[4][4];
#pragma unroll
  for (int i = 0; i < 4; ++i)
#pragma unroll
    for (int j = 0; j < 4; ++j)
      acc[i][j] = (v4f){0.f, 0.f, 0.f, 0.f};

  for (int kt = 0; kt < KITERS; ++kt){
    const int kb = kt * BK;
#pragma unroll
    for (int j = 0; j < 4; ++j){
      const int reg = wave * 4 + j;
      const int row = reg * 8 + rr;
      gl2lds16(ga + (size_t)row * IN_DIM + kb + cg * 8, &As[reg * 512 + lane * 8]);
      gl2lds16(gb + (size_t)row * IN_DIM + kb + cg * 8, &Bs[reg * 512 + lane * 8]);
    }
    __syncthreads();   // drains vmcnt; tile visible to all waves
#pragma unroll
    for (int kk = 0; kk < 2; ++kk){
      v8bf af[4], bfr[4];
#pragma unroll
      for (int i = 0; i < 4; ++i){
        const int row = wm + i*16 + c;
        const int ch  = (kk*4 + q) ^ (row & 7);
        af[i] = *reinterpret_cast<const v8bf*>(&As[row*64 + ch*8]);
      }
#pragma unroll
      for (int j = 0; j < 4; ++j){
        const int row = wn + j*16 + c;
        const int ch  = (kk*4 + q) ^ (row & 7);
        bfr[j] = *reinterpret_cast<const v8bf*>(&Bs[row*64 + ch*8]);
      }
#pragma unroll
      for (int i = 0; i < 4; ++i)
#pragma unroll
        for (int j = 0; j < 4; ++j)
          acc[i][j] = __builtin_amdgcn_mfma_f32_16x16x32_bf16(af[i], bfr[j], acc[i][j], 0, 0, 0);
    }
    __syncthreads();   // protect LDS before next tile's loads
  }

  // epilogue: contrib = tanh(h)*sigmoid(g)*w[l]; packed cols alternate V(even)/U(odd)
  float wl[4];
#pragma unroll
  for (int j = 0; j < 4; ++j)
    wl[j] = w[nblk*64 + (wn >> 1) + j*8 + (c >> 1)];

  const int codd = c & 1;
#pragma unroll
  for (int i = 0; i < 4; ++i){
    float rs[4] = {0.f, 0.f, 0.f, 0.f};
#pragma unroll
    for (int j = 0; j < 4; ++j){
#pragma unroll
      for (int r = 0; r < 4; ++r){
        float val = acc[i][j][r];
        // even lane computes tanh (V col), odd lane computes sigmoid (U col)
        float y = codd ? val : 2.f*val;
        float s = 1.f / (1.f + __expf(-y));
        float t = codd ? s : (2.f*s - 1.f);
        float part = __shfl_xor(t, 1, 64);
        rs[r] += codd ? 0.f : (t * part * wl[j]);
      }
    }
#pragma unroll
    for (int r = 0; r < 4; ++r){
      float v2 = rs[r];
      v2 += __shfl_xor(v2, 1, 64);
      v2 += __shfl_xor(v2, 2, 64);
      v2 += __shfl_xor(v2, 4, 64);
      v2 += __shfl_xor(v2, 8, 64);
      if (c == 0) atomicAdd(&ssum[wm + i*16 + q*4 + r], v2);
    }
  }
  __syncthreads();
  if (tid < BM) partial[(size_t)nblk * M_TOT + m0 + tid] = ssum[tid];
}

__global__ void softmax_inst(const float* __restrict__ partial, float* __restrict__ out){
  __shared__ float red[N_INST];
  const int b = blockIdx.x;
  const int n = threadIdx.x;
  float s = 0.f;
#pragma unroll
  for (int i = 0; i < 8; ++i) s += partial[(size_t)i * M_TOT + n*BATCH + b];
  red[n] = s; __syncthreads();
  for (int st = N_INST/2; st > 0; st >>= 1){
    if (n < st) red[n] = fmaxf(red[n], red[n + st]);
    __syncthreads();
  }
  float mx = red[0]; __syncthreads();
  float e = __expf(s - mx);
  red[n] = e; __syncthreads();
  for (int st = N_INST/2; st > 0; st >>= 1){
    if (n < st) red[n] += red[n + st];
    __syncthreads();
  }
  out[n*BATCH + b] = e / red[0];
}

extern "C" void kernel_launch(void* const* d_in, const int* in_sizes, int n_in,
                              void* d_out, int out_size, void* d_ws, size_t ws_size,
                              hipStream_t stream) {
  const float* x = (const float*)d_in[0];
  const float* v = (const float*)d_in[1];
  const float* u = (const float*)d_in[2];
  const float* w = (const float*)d_in[3];
  u16*   xb      = (u16*)d_ws;
  u16*   wpk     = (u16*)((char*)d_ws + XB_BYTES);
  float* partial = (float*)((char*)d_ws + XB_BYTES + WPK_BYTES);
  float* out     = (float*)d_out;

  prep<<<dim3(PREP_XBLKS + 512), dim3(256), 0, stream>>>(x, v, u, xb, wpk);
  gemm_score<<<dim3(2048), dim3(256), 0, stream>>>(xb, wpk, w, partial);
  softmax_inst<<<dim3(BATCH), dim3(N_INST), 0, stream>>>(partial, out);
}